// Round 3
// baseline (352.590 us; speedup 1.0000x reference)
//
#include <hip/hip_runtime.h>

// ---------- helpers ----------
__device__ __forceinline__ float bf2f(unsigned short u) {
    unsigned int v = ((unsigned int)u) << 16;
    return __builtin_bit_cast(float, v);
}
__device__ __forceinline__ unsigned short f2bf(float f) {
    unsigned int u = __builtin_bit_cast(unsigned int, f);
    unsigned int r = (u + 0x7fffu + ((u >> 16) & 1u)) >> 16;
    return (unsigned short)r;
}
__device__ __forceinline__ float sigmoidf_fast(float x) {
    return 1.f / (1.f + __expf(-x));
}

// dtype-adaptive scalar load: F32 -> read float, else read bf16 ushort
template<bool F32>
__device__ __forceinline__ float ld(const void* p, int i) {
    if constexpr (F32) return ((const float*)p)[i];
    else               return bf2f(((const unsigned short*)p)[i]);
}

#define NTOT   6422528   // 16*56*56*128
#define NPERB  401408    // 56*56*128
#define HH     56
#define WW     56
#define CC     128

// SAT box sum, window rows [i-hk+1, i+hk] (TF/JAX SAME padding for even k=2*hk)
__device__ __forceinline__ float boxsum(const float* __restrict__ p, int i, int j, int hk) {
    int y1 = min(i + hk, HH - 1);
    int y0 = i - hk;
    int x1 = min(j + hk, WW - 1);
    int x0 = j - hk;
    float s = p[(y1 * WW + x1) * CC];
    if (y0 >= 0)            s -= p[(y0 * WW + x1) * CC];
    if (x0 >= 0)            s -= p[(y1 * WW + x0) * CC];
    if (y0 >= 0 && x0 >= 0) s += p[(y0 * WW + x0) * CC];
    return fmaxf(s, 0.f);
}

// ---------- K0: dtype probe ----------
// Even-indexed ushorts: genuine bf16 Gaussians if data is bf16 (0 weird);
// f32 mantissa low-halves if data is f32 (~46% weird).
__global__ void k_probe(const unsigned short* __restrict__ xu, int* __restrict__ flag) {
    if (threadIdx.x == 0) {
        int weird = 0;
        for (int i = 0; i < 256; i++) {
            float v = bf2f(xu[2 * i]);
            if (!(fabsf(v) < 1000.f)) weird++;   // NaN also counts
        }
        *flag = (weird > 16) ? 1 : 0;            // 1 => buffers are float32
    }
}

// ---------- K1: per-sample min/max partials ----------
template<bool F32>
__device__ __forceinline__ void minmax_scan(const void* x, float& mn, float& mx) {
    int b = blockIdx.x >> 6, nb = blockIdx.x & 63;
    int base = b * NPERB + nb * 6272;
    mn = 3.4e38f; mx = -3.4e38f;
    if constexpr (F32) {
        const float4* p = (const float4*)((const float*)x + base);
        for (int v = threadIdx.x; v < 1568; v += 256) {
            float4 q = p[v];
            mn = fminf(mn, fminf(fminf(q.x, q.y), fminf(q.z, q.w)));
            mx = fmaxf(mx, fmaxf(fmaxf(q.x, q.y), fmaxf(q.z, q.w)));
        }
    } else {
        const uint4* p = (const uint4*)((const unsigned short*)x + base);
        for (int v = threadIdx.x; v < 784; v += 256) {
            uint4 q = p[v];
            unsigned int w[4] = {q.x, q.y, q.z, q.w};
#pragma unroll
            for (int k = 0; k < 4; k++) {
                float f0 = __builtin_bit_cast(float, w[k] << 16);
                float f1 = __builtin_bit_cast(float, w[k] & 0xffff0000u);
                mn = fminf(mn, fminf(f0, f1));
                mx = fmaxf(mx, fmaxf(f0, f1));
            }
        }
    }
}

__global__ void k_minmax(const int* __restrict__ flag, const void* __restrict__ x,
                         float* __restrict__ mnp, float* __restrict__ mxp) {
    float mn, mx;
    if (*flag) minmax_scan<true>(x, mn, mx);
    else       minmax_scan<false>(x, mn, mx);
#pragma unroll
    for (int off = 32; off >= 1; off >>= 1) {
        mn = fminf(mn, __shfl_xor(mn, off));
        mx = fmaxf(mx, __shfl_xor(mx, off));
    }
    __shared__ float smn[4], smx[4];
    int wid = threadIdx.x >> 6;
    if ((threadIdx.x & 63) == 0) { smn[wid] = mn; smx[wid] = mx; }
    __syncthreads();
    if (threadIdx.x == 0) {
        mn = fminf(fminf(smn[0], smn[1]), fminf(smn[2], smn[3]));
        mx = fmaxf(fmaxf(smx[0], smx[1]), fmaxf(smx[2], smx[3]));
        mnp[blockIdx.x] = mn;
        mxp[blockIdx.x] = mx;
    }
}

// ---------- K2: finalize min/max, kappa constants, zero squeeze ----------
template<bool F32>
__device__ __forceinline__ void kap_consts(const void* kap, float* dcs) {
    float v[5];
    float mean = 0.f;
#pragma unroll
    for (int s = 0; s < 5; s++) {
        float lr = 0.6931471805599453f * (float)(s + 1);
        float kp = ld<F32>(kap, s);
        float k_ = 1.f / (1.f + expf(-kp));
        float lk = 1.f / (1.f + expf(-logf(k_ + 1e-7f)));
        v[s] = lk + lr;
        mean += v[s];
    }
    mean *= 0.2f;
    float nd = 0.f;
#pragma unroll
    for (int s = 0; s < 5; s++) {
        float d = v[s] - mean;
        dcs[s] = d;
        nd += d * d;
    }
    dcs[5] = sqrtf(nd);
}

__global__ void k_prep(const int* __restrict__ flag, const void* __restrict__ kap,
                       const float* __restrict__ mnp, const float* __restrict__ mxp,
                       float* __restrict__ xmn, float* __restrict__ xiv,
                       float* __restrict__ dcs, float* __restrict__ sq) {
    int t = threadIdx.x;
    for (int k = t; k < 2048; k += 256) sq[k] = 0.f;
    if (t < 16) {
        float mn = 3.4e38f, mx = -3.4e38f;
        for (int k = 0; k < 64; k++) {
            mn = fminf(mn, mnp[t * 64 + k]);
            mx = fmaxf(mx, mxp[t * 64 + k]);
        }
        xmn[t] = mn;
        xiv[t] = 1.f / (mx - mn + 1e-7f);
    } else if (t == 32) {
        if (*flag) kap_consts<true>(kap, dcs);
        else       kap_consts<false>(kap, dcs);
    }
}

// ---------- K3: column prefix sums of xs -> SAT ----------
template<bool F32>
__device__ __forceinline__ void colsum_impl(const void* x, float* __restrict__ SAT,
                                            const float* __restrict__ xmn,
                                            const float* __restrict__ xiv) {
    int t = blockIdx.x * 256 + threadIdx.x;   // 114688 threads
    int b = t / 7168;
    int r = t % 7168;                          // j*128 + c
    float xm = xmn[b], xi = xiv[b];
    int base = b * NPERB + r;
    float acc = 0.f;
    for (int i = 0; i < HH; i++) {
        acc += (ld<F32>(x, base + i * 7168) - xm) * xi;
        SAT[base + i * 7168] = acc;
    }
}

__global__ void k_colsum(const int* __restrict__ flag, const void* __restrict__ x,
                         float* __restrict__ SAT,
                         const float* __restrict__ xmn, const float* __restrict__ xiv) {
    if (*flag) colsum_impl<true>(x, SAT, xmn, xiv);
    else       colsum_impl<false>(x, SAT, xmn, xiv);
}

// ---------- K4: in-place row prefix sums -> full SAT ----------
__global__ void k_rowsum(float* __restrict__ SAT) {
    int t = blockIdx.x * 256 + threadIdx.x;
    int b = t / 7168;
    int r = t % 7168;
    int i = r >> 7, c = r & 127;
    int base = b * NPERB + i * 7168 + c;
    float acc = 0.f;
    for (int j = 0; j < WW; j++) {
        acc += SAT[base + j * 128];
        SAT[base + j * 128] = acc;
    }
}

// ---------- K5: alphas -> squeeze accumulation ----------
// OLS weights over xc = ln2*{-2,-1,0,1,2}: middle scale (k=8) has weight 0.
__global__ void k_alpha_squeeze(const float* __restrict__ SAT, float* __restrict__ sq) {
    int b = blockIdx.x / HH, i = blockIdx.x % HH;
    int c = threadIdx.x & 127, half = threadIdx.x >> 7;
    const float* p = SAT + b * NPERB + c;
    float asum = 0.f;
    for (int j = half; j < WW; j += 2) {
        float l0 = __logf(boxsum(p, i, j, 1)  + 1e-7f);
        float l1 = __logf(boxsum(p, i, j, 2)  + 1e-7f);
        float l3 = __logf(boxsum(p, i, j, 8)  + 1e-7f);
        float l4 = __logf(boxsum(p, i, j, 16) + 1e-7f);
        asum += (-2.f * l0 - l1 + l3 + 2.f * l4);
    }
    asum *= 0.14426950408889634f;   // 1/(10*ln2)
    __shared__ float red[256];
    red[threadIdx.x] = asum;
    __syncthreads();
    if (threadIdx.x < 128)
        atomicAdd(&sq[b * 128 + threadIdx.x], red[threadIdx.x] + red[threadIdx.x + 128]);
}

// ---------- K6: squeeze-and-excite MLP ----------
template<bool F32>
__device__ __forceinline__ void se_impl(const float* __restrict__ sq,
                                        const void* W1, const void* b1,
                                        const void* W2, const void* b2,
                                        float* __restrict__ exc) {
    __shared__ float sqs[2048];
    __shared__ float hid[256];
    int t = threadIdx.x;
    for (int k = t; k < 2048; k += 256) sqs[k] = sq[k] * (1.f / 3136.f);
    __syncthreads();
    {
        int b = t >> 4, h = t & 15;
        float acc = ld<F32>(b1, h);
        for (int c2 = 0; c2 < 128; c2++) acc += sqs[b * 128 + c2] * ld<F32>(W1, c2 * 16 + h);
        hid[b * 16 + h] = fmaxf(acc, 0.f);
    }
    __syncthreads();
    for (int k = t; k < 2048; k += 256) {
        int b = k >> 7, c2 = k & 127;
        float acc = ld<F32>(b2, c2);
#pragma unroll
        for (int h = 0; h < 16; h++) acc += hid[b * 16 + h] * ld<F32>(W2, h * 128 + c2);
        exc[k] = sigmoidf_fast(acc);
    }
}

__global__ void k_se(const int* __restrict__ flag, const float* __restrict__ sq,
                     const void* W1, const void* b1, const void* W2, const void* b2,
                     float* __restrict__ exc) {
    if (*flag) se_impl<true>(sq, W1, b1, W2, b2, exc);
    else       se_impl<false>(sq, W1, b1, W2, b2, exc);
}

// ---------- K7: final fused elementwise ----------
// F32 governs BOTH input reads and output writes (uniform buffer dtype).
template<bool F32>
__device__ __forceinline__ void final_impl(const float* __restrict__ SAT, const void* x,
                                           const void* g_, const void* be_,
                                           const void* bm_, const void* bv_,
                                           const float* __restrict__ xmn, const float* __restrict__ xiv,
                                           const float* __restrict__ dcs, const float* __restrict__ exc,
                                           void* __restrict__ out) {
    int b = blockIdx.x / HH, i = blockIdx.x % HH;
    int c = threadIdx.x & 127, half = threadIdx.x >> 7;
    const float* p = SAT + b * NPERB + c;
    float gam = ld<F32>(g_, c), bet = ld<F32>(be_, c), bmn = ld<F32>(bm_, c);
    float rs  = rsqrtf(ld<F32>(bv_, c) + 1e-3f);
    float xm = xmn[b], xi = xiv[b], e = exc[b * 128 + c];
    float d0 = dcs[0], d1 = dcs[1], d2 = dcs[2], d3 = dcs[3], d4 = dcs[4], nd = dcs[5];
    int rowbase = b * NPERB + i * 7168 + c;
    for (int j = half; j < WW; j += 2) {
        float l0 = __logf(boxsum(p, i, j, 1)  + 1e-7f);
        float l1 = __logf(boxsum(p, i, j, 2)  + 1e-7f);
        float l2 = __logf(boxsum(p, i, j, 4)  + 1e-7f);
        float l3 = __logf(boxsum(p, i, j, 8)  + 1e-7f);
        float l4 = __logf(boxsum(p, i, j, 16) + 1e-7f);
        float L1 = l0 + l1 + l2 + l3 + l4;
        float alphas = (-2.f * l0 - l1 + l3 + 2.f * l4) * 0.14426950408889634f;
        float mean = 0.2f * L1;
        float a0 = l0 - mean, a1 = l1 - mean, a2 = l2 - mean, a3 = l3 - mean, a4 = l4 - mean;
        float na2  = a0 * a0 + a1 * a1 + a2 * a2 + a3 * a3 + a4 * a4;
        float adot = a0 * d0 + a1 * d1 + a2 * d2 + a3 * d3 + a4 * d4;
        float na = sqrtf(fmaxf(na2, 0.f));
        float cosv = (alphas * adot) / (na * fabsf(alphas) * nd + 1e-7f);
        float sim = 0.5f * (cosv + 1.f);
        float an = gam * (alphas - bmn) * rs + bet;
        float sbn = sigmoidf_fast(an);
        float xs = (ld<F32>(x, rowbase + j * 128) - xm) * xi;
        float o = sim * sbn + (1.f - sim) * xs * e;
        if constexpr (F32) ((float*)out)[rowbase + j * 128] = o;
        else               ((unsigned short*)out)[rowbase + j * 128] = f2bf(o);
    }
}

__global__ void k_final(const int* __restrict__ flag,
                        const float* __restrict__ SAT, const void* x,
                        const void* g_, const void* be_, const void* bm_, const void* bv_,
                        const float* __restrict__ xmn, const float* __restrict__ xiv,
                        const float* __restrict__ dcs, const float* __restrict__ exc,
                        void* __restrict__ out) {
    if (*flag) final_impl<true>(SAT, x, g_, be_, bm_, bv_, xmn, xiv, dcs, exc, out);
    else       final_impl<false>(SAT, x, g_, be_, bm_, bv_, xmn, xiv, dcs, exc, out);
}

extern "C" void kernel_launch(void* const* d_in, const int* in_sizes, int n_in,
                              void* d_out, int out_size, void* d_ws, size_t ws_size,
                              hipStream_t stream) {
    const void* x   = d_in[0];
    const void* kap = d_in[1];
    const void* W1  = d_in[2];
    const void* b1  = d_in[3];
    const void* W2  = d_in[4];
    const void* b2  = d_in[5];
    const void* gam = d_in[6];
    const void* bet = d_in[7];
    const void* bnm = d_in[8];
    const void* bnv = d_in[9];

    float* SAT = (float*)d_ws;          // NTOT floats
    float* sq  = SAT + NTOT;            // 2048
    float* mnp = sq + 2048;             // 1024
    float* mxp = mnp + 1024;            // 1024
    float* xmn = mxp + 1024;            // 16
    float* xiv = xmn + 16;              // 16
    float* dcs = xiv + 16;              // 8
    float* exc = dcs + 8;               // 2048
    int*   flg = (int*)(exc + 2048);    // 1

    k_probe<<<1, 64, 0, stream>>>((const unsigned short*)x, flg);
    k_minmax<<<1024, 256, 0, stream>>>(flg, x, mnp, mxp);
    k_prep<<<1, 256, 0, stream>>>(flg, kap, mnp, mxp, xmn, xiv, dcs, sq);
    k_colsum<<<448, 256, 0, stream>>>(flg, x, SAT, xmn, xiv);
    k_rowsum<<<448, 256, 0, stream>>>(SAT);
    k_alpha_squeeze<<<896, 256, 0, stream>>>(SAT, sq);
    k_se<<<1, 256, 0, stream>>>(flg, sq, W1, b1, W2, b2, exc);
    k_final<<<896, 256, 0, stream>>>(flg, SAT, x, gam, bet, bnm, bnv, xmn, xiv, dcs, exc, d_out);
}

// Round 4
// 202.474 us; speedup vs baseline: 1.7414x; 1.7414x over previous
//
#include <hip/hip_runtime.h>

// ---------- helpers ----------
__device__ __forceinline__ float bf2f(unsigned short u) {
    unsigned int v = ((unsigned int)u) << 16;
    return __builtin_bit_cast(float, v);
}
__device__ __forceinline__ unsigned short f2bf(float f) {
    unsigned int u = __builtin_bit_cast(unsigned int, f);
    unsigned int r = (u + 0x7fffu + ((u >> 16) & 1u)) >> 16;
    return (unsigned short)r;
}
__device__ __forceinline__ float sigmoidf_fast(float x) {
    return 1.f / (1.f + __expf(-x));
}

// dtype-adaptive scalar load: F32 -> read float, else read bf16 ushort
template<bool F32>
__device__ __forceinline__ float ld(const void* p, int i) {
    if constexpr (F32) return ((const float*)p)[i];
    else               return bf2f(((const unsigned short*)p)[i]);
}

#define NTOT   6422528   // 16*56*56*128
#define NPERB  401408    // 56*56*128
#define HH     56
#define WW     56
#define CC     128

// SAT box sum, window rows [i-hk+1, i+hk] (TF/JAX SAME padding for even k=2*hk)
__device__ __forceinline__ float boxsum(const float* __restrict__ p, int i, int j, int hk) {
    int y1 = min(i + hk, HH - 1);
    int y0 = i - hk;
    int x1 = min(j + hk, WW - 1);
    int x0 = j - hk;
    float s = p[(y1 * WW + x1) * CC];
    if (y0 >= 0)            s -= p[(y0 * WW + x1) * CC];
    if (x0 >= 0)            s -= p[(y1 * WW + x0) * CC];
    if (y0 >= 0 && x0 >= 0) s += p[(y0 * WW + x0) * CC];
    return fmaxf(s, 0.f);
}

// ---------- K0: dtype probe ----------
__global__ void k_probe(const unsigned short* __restrict__ xu, int* __restrict__ flag) {
    if (threadIdx.x == 0) {
        int weird = 0;
        for (int i = 0; i < 256; i++) {
            float v = bf2f(xu[2 * i]);
            if (!(fabsf(v) < 1000.f)) weird++;   // NaN also counts
        }
        *flag = (weird > 16) ? 1 : 0;            // 1 => buffers are float32
    }
}

// ---------- K1: per-sample min/max partials ----------
template<bool F32>
__device__ __forceinline__ void minmax_scan(const void* x, float& mn, float& mx) {
    int b = blockIdx.x >> 6, nb = blockIdx.x & 63;
    int base = b * NPERB + nb * 6272;
    mn = 3.4e38f; mx = -3.4e38f;
    if constexpr (F32) {
        const float4* p = (const float4*)((const float*)x + base);
        for (int v = threadIdx.x; v < 1568; v += 256) {
            float4 q = p[v];
            mn = fminf(mn, fminf(fminf(q.x, q.y), fminf(q.z, q.w)));
            mx = fmaxf(mx, fmaxf(fmaxf(q.x, q.y), fmaxf(q.z, q.w)));
        }
    } else {
        const uint4* p = (const uint4*)((const unsigned short*)x + base);
        for (int v = threadIdx.x; v < 784; v += 256) {
            uint4 q = p[v];
            unsigned int w[4] = {q.x, q.y, q.z, q.w};
#pragma unroll
            for (int k = 0; k < 4; k++) {
                float f0 = __builtin_bit_cast(float, w[k] << 16);
                float f1 = __builtin_bit_cast(float, w[k] & 0xffff0000u);
                mn = fminf(mn, fminf(f0, f1));
                mx = fmaxf(mx, fmaxf(f0, f1));
            }
        }
    }
}

__global__ void k_minmax(const int* __restrict__ flag, const void* __restrict__ x,
                         float* __restrict__ mnp, float* __restrict__ mxp) {
    float mn, mx;
    if (*flag) minmax_scan<true>(x, mn, mx);
    else       minmax_scan<false>(x, mn, mx);
#pragma unroll
    for (int off = 32; off >= 1; off >>= 1) {
        mn = fminf(mn, __shfl_xor(mn, off));
        mx = fmaxf(mx, __shfl_xor(mx, off));
    }
    __shared__ float smn[4], smx[4];
    int wid = threadIdx.x >> 6;
    if ((threadIdx.x & 63) == 0) { smn[wid] = mn; smx[wid] = mx; }
    __syncthreads();
    if (threadIdx.x == 0) {
        mn = fminf(fminf(smn[0], smn[1]), fminf(smn[2], smn[3]));
        mx = fmaxf(fmaxf(smx[0], smx[1]), fmaxf(smx[2], smx[3]));
        mnp[blockIdx.x] = mn;
        mxp[blockIdx.x] = mx;
    }
}

// ---------- K2: finalize min/max, kappa constants, zero squeeze ----------
template<bool F32>
__device__ __forceinline__ void kap_consts(const void* kap, float* dcs) {
    float v[5];
    float mean = 0.f;
#pragma unroll
    for (int s = 0; s < 5; s++) {
        float lr = 0.6931471805599453f * (float)(s + 1);
        float kp = ld<F32>(kap, s);
        float k_ = 1.f / (1.f + expf(-kp));
        float lk = 1.f / (1.f + expf(-logf(k_ + 1e-7f)));
        v[s] = lk + lr;
        mean += v[s];
    }
    mean *= 0.2f;
    float nd = 0.f;
#pragma unroll
    for (int s = 0; s < 5; s++) {
        float d = v[s] - mean;
        dcs[s] = d;
        nd += d * d;
    }
    dcs[5] = sqrtf(nd);
}

__global__ void k_prep(const int* __restrict__ flag, const void* __restrict__ kap,
                       const float* __restrict__ mnp, const float* __restrict__ mxp,
                       float* __restrict__ xmn, float* __restrict__ xiv,
                       float* __restrict__ dcs, float* __restrict__ sq) {
    int t = threadIdx.x;
    for (int k = t; k < 2048; k += 256) sq[k] = 0.f;
    if (t < 16) {
        float mn = 3.4e38f, mx = -3.4e38f;
        for (int k = 0; k < 64; k++) {
            mn = fminf(mn, mnp[t * 64 + k]);
            mx = fmaxf(mx, mxp[t * 64 + k]);
        }
        xmn[t] = mn;
        xiv[t] = 1.f / (mx - mn + 1e-7f);
    } else if (t == 32) {
        if (*flag) kap_consts<true>(kap, dcs);
        else       kap_consts<false>(kap, dcs);
    }
}

// ---------- K3: column prefix sums of xs -> SAT ----------
template<bool F32>
__device__ __forceinline__ void colsum_impl(const void* x, float* __restrict__ SAT,
                                            const float* __restrict__ xmn,
                                            const float* __restrict__ xiv) {
    int t = blockIdx.x * 256 + threadIdx.x;   // 114688 threads
    int b = t / 7168;
    int r = t % 7168;                          // j*128 + c
    float xm = xmn[b], xi = xiv[b];
    int base = b * NPERB + r;
    float acc = 0.f;
    for (int i = 0; i < HH; i++) {
        acc += (ld<F32>(x, base + i * 7168) - xm) * xi;
        SAT[base + i * 7168] = acc;
    }
}

__global__ void k_colsum(const int* __restrict__ flag, const void* __restrict__ x,
                         float* __restrict__ SAT,
                         const float* __restrict__ xmn, const float* __restrict__ xiv) {
    if (*flag) colsum_impl<true>(x, SAT, xmn, xiv);
    else       colsum_impl<false>(x, SAT, xmn, xiv);
}

// ---------- K4: in-place row prefix sums -> full SAT ----------
__global__ void k_rowsum(float* __restrict__ SAT) {
    int t = blockIdx.x * 256 + threadIdx.x;
    int b = t / 7168;
    int r = t % 7168;
    int i = r >> 7, c = r & 127;
    int base = b * NPERB + i * 7168 + c;
    float acc = 0.f;
    for (int j = 0; j < WW; j++) {
        acc += SAT[base + j * 128];
        SAT[base + j * 128] = acc;
    }
}

// ---------- K5: fused gather: A/B emit + squeeze accumulation ----------
// MODE: 0 = A/B as two f32 arrays, 1 = packed bf16x2 in one u32 array
template<bool F32, int MODE>
__device__ __forceinline__ void gather_impl(const float* __restrict__ SAT, const void* x,
                                            const void* g_, const void* be_,
                                            const void* bm_, const void* bv_,
                                            const float* __restrict__ xmn, const float* __restrict__ xiv,
                                            const float* __restrict__ dcs,
                                            float* __restrict__ sq, void* __restrict__ AB) {
    // XCD slab swizzle: physical blocks p%8==k (assumed XCD k) cover contiguous
    // logical slab of 2 samples -> per-XCD SAT working set 3.14 MB < 4 MiB L2.
    int p_ = blockIdx.x;                    // 3584 blocks
    int L  = (p_ & 7) * 448 + (p_ >> 3);
    int b = L / 224, rem = L % 224;
    int i = rem >> 2, q = rem & 3;
    int c = threadIdx.x & 127, half = threadIdx.x >> 7;
    const float* p = SAT + b * NPERB + c;
    float gam = ld<F32>(g_, c), bet = ld<F32>(be_, c), bmn = ld<F32>(bm_, c);
    float rs  = rsqrtf(ld<F32>(bv_, c) + 1e-3f);
    float xm = xmn[b], xi = xiv[b];
    float d0 = dcs[0], d1 = dcs[1], d2 = dcs[2], d3 = dcs[3], d4 = dcs[4], nd = dcs[5];
    float asum = 0.f;
    int j0 = q * 14 + half * 7;
    for (int jj = 0; jj < 7; jj++) {
        int j = j0 + jj;
        float l0 = __logf(boxsum(p, i, j, 1)  + 1e-7f);
        float l1 = __logf(boxsum(p, i, j, 2)  + 1e-7f);
        float l2 = __logf(boxsum(p, i, j, 4)  + 1e-7f);
        float l3 = __logf(boxsum(p, i, j, 8)  + 1e-7f);
        float l4 = __logf(boxsum(p, i, j, 16) + 1e-7f);
        float w  = -2.f * l0 - l1 + l3 + 2.f * l4;
        asum += w;
        float alphas = w * 0.14426950408889634f;  // 1/(10*ln2)
        float mean = 0.2f * (l0 + l1 + l2 + l3 + l4);
        float a0 = l0 - mean, a1 = l1 - mean, a2 = l2 - mean, a3 = l3 - mean, a4 = l4 - mean;
        float na2  = a0 * a0 + a1 * a1 + a2 * a2 + a3 * a3 + a4 * a4;
        float adot = a0 * d0 + a1 * d1 + a2 * d2 + a3 * d3 + a4 * d4;
        float na = sqrtf(fmaxf(na2, 0.f));
        float cosv = (alphas * adot) / (na * fabsf(alphas) * nd + 1e-7f);
        float sim = 0.5f * (cosv + 1.f);
        float sbn = sigmoidf_fast(gam * (alphas - bmn) * rs + bet);
        int idx = b * NPERB + i * 7168 + j * 128 + c;
        float xs = (ld<F32>(x, idx) - xm) * xi;
        float A = sim * sbn;
        float B = (1.f - sim) * xs;
        if constexpr (MODE == 0) {
            ((float*)AB)[idx] = A;
            ((float*)AB)[NTOT + idx] = B;
        } else {
            ((unsigned int*)AB)[idx] = ((unsigned int)f2bf(B) << 16) | f2bf(A);
        }
    }
    asum *= 0.14426950408889634f;
    __shared__ float red[256];
    red[threadIdx.x] = asum;
    __syncthreads();
    if (threadIdx.x < 128)
        atomicAdd(&sq[b * 128 + threadIdx.x], red[threadIdx.x] + red[threadIdx.x + 128]);
}

template<int MODE>
__global__ void k_gather(const int* __restrict__ flag, const float* __restrict__ SAT,
                         const void* x, const void* g_, const void* be_,
                         const void* bm_, const void* bv_,
                         const float* __restrict__ xmn, const float* __restrict__ xiv,
                         const float* __restrict__ dcs,
                         float* __restrict__ sq, void* __restrict__ AB) {
    if (*flag) gather_impl<true, MODE>(SAT, x, g_, be_, bm_, bv_, xmn, xiv, dcs, sq, AB);
    else       gather_impl<false, MODE>(SAT, x, g_, be_, bm_, bv_, xmn, xiv, dcs, sq, AB);
}

// ---------- K6: squeeze-and-excite MLP ----------
template<bool F32>
__device__ __forceinline__ void se_impl(const float* __restrict__ sq,
                                        const void* W1, const void* b1,
                                        const void* W2, const void* b2,
                                        float* __restrict__ exc) {
    __shared__ float sqs[2048];
    __shared__ float hid[256];
    int t = threadIdx.x;
    for (int k = t; k < 2048; k += 256) sqs[k] = sq[k] * (1.f / 3136.f);
    __syncthreads();
    {
        int b = t >> 4, h = t & 15;
        float acc = ld<F32>(b1, h);
        for (int c2 = 0; c2 < 128; c2++) acc += sqs[b * 128 + c2] * ld<F32>(W1, c2 * 16 + h);
        hid[b * 16 + h] = fmaxf(acc, 0.f);
    }
    __syncthreads();
    for (int k = t; k < 2048; k += 256) {
        int b = k >> 7, c2 = k & 127;
        float acc = ld<F32>(b2, c2);
#pragma unroll
        for (int h = 0; h < 16; h++) acc += hid[b * 16 + h] * ld<F32>(W2, h * 128 + c2);
        exc[k] = sigmoidf_fast(acc);
    }
}

__global__ void k_se(const int* __restrict__ flag, const float* __restrict__ sq,
                     const void* W1, const void* b1, const void* W2, const void* b2,
                     float* __restrict__ exc) {
    if (*flag) se_impl<true>(sq, W1, b1, W2, b2, exc);
    else       se_impl<false>(sq, W1, b1, W2, b2, exc);
}

// ---------- K7: light streaming mix: out = A + B * excite ----------
template<int MODE>
__global__ void k_mix(const int* __restrict__ flag, const void* __restrict__ AB,
                      const float* __restrict__ exc, void* __restrict__ out) {
    int t = blockIdx.x * 256 + threadIdx.x;    // 1,605,632 float4-groups
    int flat = t * 4;
    int b = flat / NPERB;
    int cb = flat & 127;
    float4 e4 = *(const float4*)(exc + b * 128 + cb);
    float A[4], B[4];
    if constexpr (MODE == 0) {
        float4 a4 = ((const float4*)AB)[t];
        float4 b4 = ((const float4*)((const float*)AB + NTOT))[t];
        A[0]=a4.x; A[1]=a4.y; A[2]=a4.z; A[3]=a4.w;
        B[0]=b4.x; B[1]=b4.y; B[2]=b4.z; B[3]=b4.w;
    } else {
        uint4 u = ((const uint4*)AB)[t];
        unsigned int w[4] = {u.x, u.y, u.z, u.w};
#pragma unroll
        for (int k = 0; k < 4; k++) {
            A[k] = bf2f((unsigned short)(w[k] & 0xffffu));
            B[k] = bf2f((unsigned short)(w[k] >> 16));
        }
    }
    float e[4] = {e4.x, e4.y, e4.z, e4.w};
    float o[4];
#pragma unroll
    for (int k = 0; k < 4; k++) o[k] = A[k] + B[k] * e[k];
    if (*flag) {
        ((float4*)out)[t] = make_float4(o[0], o[1], o[2], o[3]);
    } else {
        ushort4 s;
        s.x = f2bf(o[0]); s.y = f2bf(o[1]); s.z = f2bf(o[2]); s.w = f2bf(o[3]);
        ((ushort4*)out)[t] = s;
    }
}

// ---------- fallback kernels (small-ws path): old 2-pass structure ----------
__global__ void k_alpha_squeeze(const float* __restrict__ SAT, float* __restrict__ sq) {
    int b = blockIdx.x / HH, i = blockIdx.x % HH;
    int c = threadIdx.x & 127, half = threadIdx.x >> 7;
    const float* p = SAT + b * NPERB + c;
    float asum = 0.f;
    for (int j = half; j < WW; j += 2) {
        float l0 = __logf(boxsum(p, i, j, 1)  + 1e-7f);
        float l1 = __logf(boxsum(p, i, j, 2)  + 1e-7f);
        float l3 = __logf(boxsum(p, i, j, 8)  + 1e-7f);
        float l4 = __logf(boxsum(p, i, j, 16) + 1e-7f);
        asum += (-2.f * l0 - l1 + l3 + 2.f * l4);
    }
    asum *= 0.14426950408889634f;
    __shared__ float red[256];
    red[threadIdx.x] = asum;
    __syncthreads();
    if (threadIdx.x < 128)
        atomicAdd(&sq[b * 128 + threadIdx.x], red[threadIdx.x] + red[threadIdx.x + 128]);
}

template<bool F32>
__device__ __forceinline__ void final_impl(const float* __restrict__ SAT, const void* x,
                                           const void* g_, const void* be_,
                                           const void* bm_, const void* bv_,
                                           const float* __restrict__ xmn, const float* __restrict__ xiv,
                                           const float* __restrict__ dcs, const float* __restrict__ exc,
                                           void* __restrict__ out) {
    int b = blockIdx.x / HH, i = blockIdx.x % HH;
    int c = threadIdx.x & 127, half = threadIdx.x >> 7;
    const float* p = SAT + b * NPERB + c;
    float gam = ld<F32>(g_, c), bet = ld<F32>(be_, c), bmn = ld<F32>(bm_, c);
    float rs  = rsqrtf(ld<F32>(bv_, c) + 1e-3f);
    float xm = xmn[b], xi = xiv[b], e = exc[b * 128 + c];
    float d0 = dcs[0], d1 = dcs[1], d2 = dcs[2], d3 = dcs[3], d4 = dcs[4], nd = dcs[5];
    int rowbase = b * NPERB + i * 7168 + c;
    for (int j = half; j < WW; j += 2) {
        float l0 = __logf(boxsum(p, i, j, 1)  + 1e-7f);
        float l1 = __logf(boxsum(p, i, j, 2)  + 1e-7f);
        float l2 = __logf(boxsum(p, i, j, 4)  + 1e-7f);
        float l3 = __logf(boxsum(p, i, j, 8)  + 1e-7f);
        float l4 = __logf(boxsum(p, i, j, 16) + 1e-7f);
        float alphas = (-2.f * l0 - l1 + l3 + 2.f * l4) * 0.14426950408889634f;
        float mean = 0.2f * (l0 + l1 + l2 + l3 + l4);
        float a0 = l0 - mean, a1 = l1 - mean, a2 = l2 - mean, a3 = l3 - mean, a4 = l4 - mean;
        float na2  = a0 * a0 + a1 * a1 + a2 * a2 + a3 * a3 + a4 * a4;
        float adot = a0 * d0 + a1 * d1 + a2 * d2 + a3 * d3 + a4 * d4;
        float na = sqrtf(fmaxf(na2, 0.f));
        float cosv = (alphas * adot) / (na * fabsf(alphas) * nd + 1e-7f);
        float sim = 0.5f * (cosv + 1.f);
        float sbn = sigmoidf_fast(gam * (alphas - bmn) * rs + bet);
        float xs = (ld<F32>(x, rowbase + j * 128) - xm) * xi;
        float o = sim * sbn + (1.f - sim) * xs * e;
        if constexpr (F32) ((float*)out)[rowbase + j * 128] = o;
        else               ((unsigned short*)out)[rowbase + j * 128] = f2bf(o);
    }
}

__global__ void k_final(const int* __restrict__ flag,
                        const float* __restrict__ SAT, const void* x,
                        const void* g_, const void* be_, const void* bm_, const void* bv_,
                        const float* __restrict__ xmn, const float* __restrict__ xiv,
                        const float* __restrict__ dcs, const float* __restrict__ exc,
                        void* __restrict__ out) {
    if (*flag) final_impl<true>(SAT, x, g_, be_, bm_, bv_, xmn, xiv, dcs, exc, out);
    else       final_impl<false>(SAT, x, g_, be_, bm_, bv_, xmn, xiv, dcs, exc, out);
}

extern "C" void kernel_launch(void* const* d_in, const int* in_sizes, int n_in,
                              void* d_out, int out_size, void* d_ws, size_t ws_size,
                              hipStream_t stream) {
    const void* x   = d_in[0];
    const void* kap = d_in[1];
    const void* W1  = d_in[2];
    const void* b1  = d_in[3];
    const void* W2  = d_in[4];
    const void* b2  = d_in[5];
    const void* gam = d_in[6];
    const void* bet = d_in[7];
    const void* bnm = d_in[8];
    const void* bnv = d_in[9];

    // choose A/B storage mode by available workspace
    const size_t small_words = 8192;
    int mode;
    if (ws_size >= (size_t)(3u * NTOT + small_words) * 4) mode = 0;        // f32 A,B
    else if (ws_size >= (size_t)(2u * NTOT + small_words) * 4) mode = 1;   // packed bf16
    else mode = 2;                                                          // fallback 2-pass

    float* SAT = (float*)d_ws;
    size_t ab_words = (mode == 0) ? 2u * NTOT : (mode == 1 ? NTOT : 0);
    float* ABp  = SAT + NTOT;
    float* smallp = ABp + ab_words;
    float* sq  = smallp;            // 2048
    float* mnp = sq + 2048;         // 1024
    float* mxp = mnp + 1024;        // 1024
    float* xmn = mxp + 1024;        // 16
    float* xiv = xmn + 16;          // 16
    float* dcs = xiv + 16;          // 8
    float* exc = dcs + 8;           // 2048
    int*   flg = (int*)(exc + 2048);

    k_probe<<<1, 64, 0, stream>>>((const unsigned short*)x, flg);
    k_minmax<<<1024, 256, 0, stream>>>(flg, x, mnp, mxp);
    k_prep<<<1, 256, 0, stream>>>(flg, kap, mnp, mxp, xmn, xiv, dcs, sq);
    k_colsum<<<448, 256, 0, stream>>>(flg, x, SAT, xmn, xiv);
    k_rowsum<<<448, 256, 0, stream>>>(SAT);

    if (mode == 2) {
        k_alpha_squeeze<<<896, 256, 0, stream>>>(SAT, sq);
        k_se<<<1, 256, 0, stream>>>(flg, sq, W1, b1, W2, b2, exc);
        k_final<<<896, 256, 0, stream>>>(flg, SAT, x, gam, bet, bnm, bnv, xmn, xiv, dcs, exc, d_out);
        return;
    }

    if (mode == 0)
        k_gather<0><<<3584, 256, 0, stream>>>(flg, SAT, x, gam, bet, bnm, bnv, xmn, xiv, dcs, sq, ABp);
    else
        k_gather<1><<<3584, 256, 0, stream>>>(flg, SAT, x, gam, bet, bnm, bnv, xmn, xiv, dcs, sq, ABp);

    k_se<<<1, 256, 0, stream>>>(flg, sq, W1, b1, W2, b2, exc);

    if (mode == 0)
        k_mix<0><<<6272, 256, 0, stream>>>(flg, ABp, exc, d_out);
    else
        k_mix<1><<<6272, 256, 0, stream>>>(flg, ABp, exc, d_out);
}